// Round 21
// baseline (34.676 us; speedup 1.0000x reference)
//
#include <hip/hip_runtime.h>
#include <hip/hip_bf16.h>

// Winograd F(2x2,3x3) via bf16 MFMA.
// x (8,64,128,128) f32, filt (64,64,3,3) f32 -> Y (8,64,126,126) f32
// Block = (n, ONE tt row, uu-HALF: 32 tiles, ALL 64 k, ALL 64 c). 512 thr = 8 waves.
// Grid 1008 = 8 n x 63 tt x 2 uuh; blockIdx&7 = n -> image pinned to one XCD.
// 4 half-passes (2 a-pairs x 2 c-halves), DOUBLE-BUFFERED V (2 x 18.4 KB):
//   transform(p+1) || GEMM(p) per barrier window; 4 independent blocks/CU.
// Wave = (mt 2, kq 4); Yp=[2][2]=16 regs (VGPR<=64 tier).
// R21: + s_setprio(1) around MFMA cluster (T5; 4 phase-diverse blocks/CU =
// the regime where setprio measured +4-7%). R20 (4-wave blocks) regressed ->
// this geometry is the family optimum.

#define T_TILES 63
#define HW 128
#define OW 126

typedef __attribute__((ext_vector_type(8))) short short8;   // 8 bf16
typedef __attribute__((ext_vector_type(4))) float f32x4;

static __device__ __forceinline__ unsigned int f2bf(float f) {
    unsigned int u = __float_as_uint(f);
    return (u + 0x7FFFu + ((u >> 16) & 1u)) >> 16;   // RNE bf16
}

static __device__ __forceinline__ unsigned int pkbf2(float lo, float hi) {
    __hip_bfloat162 t;
    t.x = __float2bfloat16(lo);
    t.y = __float2bfloat16(hi);
    unsigned int r;
    __builtin_memcpy(&r, &t, 4);
    return r;                                   // v_cvt_pk_bf16_f32
}

// U_frag layout (unchanged): frag[(ab*2+ck)*4+kq][lane 0..63][j 0..7] bf16 (128 KB)
// B-operand lane l holds B[c'=(l>>4)*8+j (+32*ck)][k=(l&15)+16*kq]
__global__ __launch_bounds__(256)
void filter_transform(const float* __restrict__ g, unsigned short* __restrict__ Uf) {
    int idx = blockIdx.x * 256 + threadIdx.x;   // k*64 + c
    if (idx >= 64 * 64) return;
    int k = idx >> 6, c = idx & 63;
    const float* gp = g + idx * 9;
    float g00 = gp[0], g01 = gp[1], g02 = gp[2];
    float g10 = gp[3], g11 = gp[4], g12 = gp[5];
    float g20 = gp[6], g21 = gp[7], g22 = gp[8];
    float w[4][3];
    w[0][0] = g00;                w[0][1] = g01;                w[0][2] = g02;
    w[1][0] = 0.5f*(g00+g10+g20); w[1][1] = 0.5f*(g01+g11+g21); w[1][2] = 0.5f*(g02+g12+g22);
    w[2][0] = 0.5f*(g00-g10+g20); w[2][1] = 0.5f*(g01-g11+g21); w[2][2] = 0.5f*(g02-g12+g22);
    w[3][0] = g20;                w[3][1] = g21;                w[3][2] = g22;

    int kq = k >> 4, kl = k & 15;
    int ck = c >> 5;
    int lane = kl + (((c & 31) >> 3) << 4);
    int j = c & 7;
    #pragma unroll
    for (int a = 0; a < 4; ++a) {
        float uv[4];
        uv[0] = w[a][0];
        uv[1] = 0.5f * (w[a][0] + w[a][1] + w[a][2]);
        uv[2] = 0.5f * (w[a][0] - w[a][1] + w[a][2]);
        uv[3] = w[a][2];
        #pragma unroll
        for (int b = 0; b < 4; ++b) {
            int ab = a * 4 + b;
            size_t off = ((size_t)((ab * 2 + ck) * 4 + kq) * 64 + lane) * 8 + j;
            Uf[off] = (unsigned short)f2bf(uv[b]);
        }
    }
}

#define VSTRIDE 72                    // bytes per tm row (64 data + 8 pad)
#define VPLANE  (32 * VSTRIDE)        // 2304 B per ab-plane (32 tiles)
#define VBUF    (8 * VPLANE)          // 18432 B per buffer; 2 buffers = 36864 B
#define YSTRIDE 130                   // f32 words per k-plane staging (2x64 + 2 pad)

__global__ __launch_bounds__(512)
void winograd_main(const float* __restrict__ x, const unsigned short* __restrict__ Uf,
                   float* __restrict__ Y) {
    __shared__ __align__(16) char smem[2 * VBUF];   // 36864 B -> 4 blocks/CU

    const int tid  = threadIdx.x;
    const int lane = tid & 63;
    const int wv   = tid >> 6;                 // 0..7

    const int n   = blockIdx.x & 7;            // XCD pin
    const int r2  = blockIdx.x >> 3;           // 0..125
    const int uuh = r2 & 1;                    // uu half
    const int tb  = r2 >> 1;                   // 0..62 (tt row)

    const int mt = wv >> 2;                    // 0..1 M-tile (16 uu each)
    const int kq = wv & 3;                     // k-quarter

    const int kl = lane & 15;
    const int g4 = lane >> 4;

    f32x4 Yp[2][2];                             // [p][q] -- 16 VGPRs
    #pragma unroll
    for (int p = 0; p < 2; ++p)
        #pragma unroll
        for (int q = 0; q < 2; ++q)
            Yp[p][q] = (f32x4){0.f, 0.f, 0.f, 0.f};

    // transform mapping: tm_loc = local uu tile (0..31), cg = c-pair group (0..15).
    // uu_g==63 (uuh=1, tm_loc=31) is padding: clamp addr; discarded in epilogue.
    const int tm_loc = tid & 31;
    const int cg     = tid >> 5;
    const int uu_g   = uuh * 32 + tm_loc;
    const int tmcg   = (uu_g < T_TILES) ? uu_g : 0;

    // A-fragment read base (within an ab plane)
    const int tmA   = mt * 16 + kl;            // 0..31
    const int abyte = tmA * VSTRIDE + g4 * 16;

    const short8* UfV = (const short8*)Uf;

    // ---- transform one half-pass hp = (P, ck) into buffer bufSel ----
    auto TRANSFORM = [&](int hp, int bufSel) {
        const int P  = hp >> 1;
        const int ck = hp & 1;
        const int xrow0 = 2 * tb + P;           // rows xrow0..xrow0+2 (max 127)
        float vv[2][8];
        #pragma unroll
        for (int hh = 0; hh < 2; ++hh) {
            const int c = ck * 32 + cg * 2 + hh;
            const float* xp = x + (((size_t)(n * 64 + c)) * HW + xrow0) * HW + 2 * tmcg;
            float ld[3][4];
            #pragma unroll
            for (int rr = 0; rr < 3; ++rr) {
                float2 lo = *reinterpret_cast<const float2*>(xp + rr * HW);
                float2 hi = *reinterpret_cast<const float2*>(xp + rr * HW + 2);
                ld[rr][0] = lo.x; ld[rr][1] = lo.y;
                ld[rr][2] = hi.x; ld[rr][3] = hi.y;
            }
            float wa[2][4];
            #pragma unroll
            for (int j = 0; j < 4; ++j) {
                if (P == 0) {
                    wa[0][j] = ld[0][j] - ld[2][j];   // a=0
                    wa[1][j] = ld[1][j] + ld[2][j];   // a=1
                } else {
                    wa[0][j] = ld[1][j] - ld[0][j];   // a=2
                    wa[1][j] = ld[0][j] - ld[2][j];   // a=3
                }
            }
            #pragma unroll
            for (int al = 0; al < 2; ++al) {
                vv[hh][al*4+0] = wa[al][0] - wa[al][2];
                vv[hh][al*4+1] = wa[al][1] + wa[al][2];
                vv[hh][al*4+2] = wa[al][2] - wa[al][1];
                vv[hh][al*4+3] = wa[al][1] - wa[al][3];
            }
        }
        const int wb = bufSel * VBUF + tm_loc * VSTRIDE + cg * 4;
        #pragma unroll
        for (int e = 0; e < 8; ++e)
            *reinterpret_cast<unsigned int*>(smem + e * VPLANE + wb) =
                pkbf2(vv[0][e], vv[1][e]);
    };

    // ---- pipeline: one barrier per half-pass; transform(p+1) || GEMM(p) ----
    TRANSFORM(0, 0);
    __syncthreads();

    #pragma unroll 1
    for (int p = 0; p < 4; ++p) {
        if (p < 3) TRANSFORM(p + 1, (p + 1) & 1);

        const int P  = p >> 1;
        const int ck = p & 1;
        const int bb = (p & 1) * VBUF;
        __builtin_amdgcn_s_setprio(1);          // T5: favor MFMA-entering waves
        #pragma unroll
        for (int aa = 0; aa < 2; ++aa) {
            const int a = 2 * P + aa;
            f32x4 acc[4];
            #pragma unroll
            for (int b = 0; b < 4; ++b) acc[b] = (f32x4){0.f, 0.f, 0.f, 0.f};
            #pragma unroll
            for (int b = 0; b < 4; ++b) {
                const char* ap = smem + bb + (aa * 4 + b) * VPLANE + abyte;
                uint2 q0 = *reinterpret_cast<const uint2*>(ap);
                uint2 q1 = *reinterpret_cast<const uint2*>(ap + 8);
                uint4 t; t.x = q0.x; t.y = q0.y; t.z = q1.x; t.w = q1.y;
                short8 Af = *reinterpret_cast<short8*>(&t);
                short8 Bf = UfV[(size_t)(((a * 4 + b) * 2 + ck) * 4 + kq) * 64 + lane];
                acc[b] = __builtin_amdgcn_mfma_f32_16x16x32_bf16(Af, Bf, acc[b], 0, 0, 0);
            }
            // fold (linear in partial sums; ck halves accumulate)
            f32x4 t0 = acc[0] + acc[1] + acc[2];
            f32x4 t1 = acc[1] - acc[2] - acc[3];
            if (a == 0) { Yp[0][0] += t0; Yp[0][1] += t1; }
            if (a == 1) { Yp[0][0] += t0; Yp[0][1] += t1;
                          Yp[1][0] += t0; Yp[1][1] += t1; }
            if (a == 2) { Yp[0][0] += t0; Yp[0][1] += t1;
                          Yp[1][0] -= t0; Yp[1][1] -= t1; }
            if (a == 3) { Yp[1][0] -= t0; Yp[1][1] -= t1; }
        }
        __builtin_amdgcn_s_setprio(0);
        __syncthreads();
    }

    // ---- store: each wave stages its 16 finished planes (no merge),
    //      then plane-contiguous copy-out (256 B row chunks) ----
    float* Ys = reinterpret_cast<float*>(smem);
    {
        const int plane = kq * 16 + kl;         // = k (0..63)
        #pragma unroll
        for (int r = 0; r < 4; ++r) {
            const int uu_loc = mt * 16 + 4 * g4 + r;   // 0..31
            if (uuh * 32 + uu_loc < T_TILES) {
                #pragma unroll
                for (int p = 0; p < 2; ++p)
                    *reinterpret_cast<float2*>(Ys + plane * YSTRIDE + p * 64 + 2 * uu_loc)
                        = make_float2(Yp[p][0][r], Yp[p][1][r]);
            }
        }
    }
    __syncthreads();

    // copy out: 64 planes x 2 rows x 32 float2 = 4096 units / 512 thr = 8 each
    #pragma unroll
    for (int i = 0; i < 8; ++i) {
        const int unit  = tid + 512 * i;        // 0..4095
        const int plane = unit >> 6;            // 0..63
        const int sub   = unit & 63;
        const int row   = sub >> 5;             // 0..1
        const int c2    = sub & 31;
        const int col_g = uuh * 64 + 2 * c2;
        if (col_g <= 124) {
            float2 v = *reinterpret_cast<const float2*>(
                Ys + plane * YSTRIDE + row * 64 + 2 * c2);
            *reinterpret_cast<float2*>(
                Y + ((size_t)(n * 64 + plane)) * (OW * OW)
                  + (size_t)(2 * tb + row) * OW + col_g) = v;
        }
    }
}

extern "C" void kernel_launch(void* const* d_in, const int* in_sizes, int n_in,
                              void* d_out, int out_size, void* d_ws, size_t ws_size,
                              hipStream_t stream) {
    const float* x    = (const float*)d_in[0];
    const float* filt = (const float*)d_in[1];
    float* Y = (float*)d_out;
    unsigned short* Uf = (unsigned short*)d_ws;    // 128 KB bf16 U fragments

    filter_transform<<<16, 256, 0, stream>>>(filt, Uf);

    winograd_main<<<dim3(1008), 512, 0, stream>>>(x, Uf, Y);
}

// Round 22
// 32.826 us; speedup vs baseline: 1.0563x; 1.0563x over previous
//
#include <hip/hip_runtime.h>
#include <hip/hip_bf16.h>

// Winograd F(2x2,3x3) via bf16 MFMA.
// x (8,64,128,128) f32, filt (64,64,3,3) f32 -> Y (8,64,126,126) f32
// Block = (n, ONE tt row, uu-HALF: 32 tiles, ALL 64 k, ALL 64 c). 512 thr = 8 waves.
// Grid 1008 = 8 n x 63 tt x 2 uuh; blockIdx&7 = n -> image pinned to one XCD.
// 4 half-passes in CK-MAJOR order (ck0P0, ck0P1, ck1P0, ck1P1) so row-sharing
// passes are adjacent -> P1's x-rows hit L1 (R19 had them 2 phases apart).
// DOUBLE-BUFFERED V (2 x 18.4 KB): transform(p+1) || GEMM(p) per barrier window;
// 4 independent blocks/CU. Wave = (mt 2, kq 4); Yp=[2][2]=16 regs (VGPR<=64 tier).
// R21 setprio regressed (barrier-locked roles) -> removed. No min-waves bound.

#define T_TILES 63
#define HW 128
#define OW 126

typedef __attribute__((ext_vector_type(8))) short short8;   // 8 bf16
typedef __attribute__((ext_vector_type(4))) float f32x4;

static __device__ __forceinline__ unsigned int f2bf(float f) {
    unsigned int u = __float_as_uint(f);
    return (u + 0x7FFFu + ((u >> 16) & 1u)) >> 16;   // RNE bf16
}

static __device__ __forceinline__ unsigned int pkbf2(float lo, float hi) {
    __hip_bfloat162 t;
    t.x = __float2bfloat16(lo);
    t.y = __float2bfloat16(hi);
    unsigned int r;
    __builtin_memcpy(&r, &t, 4);
    return r;                                   // v_cvt_pk_bf16_f32
}

// U_frag layout (unchanged): frag[(ab*2+ck)*4+kq][lane 0..63][j 0..7] bf16 (128 KB)
// B-operand lane l holds B[c'=(l>>4)*8+j (+32*ck)][k=(l&15)+16*kq]
__global__ __launch_bounds__(256)
void filter_transform(const float* __restrict__ g, unsigned short* __restrict__ Uf) {
    int idx = blockIdx.x * 256 + threadIdx.x;   // k*64 + c
    if (idx >= 64 * 64) return;
    int k = idx >> 6, c = idx & 63;
    const float* gp = g + idx * 9;
    float g00 = gp[0], g01 = gp[1], g02 = gp[2];
    float g10 = gp[3], g11 = gp[4], g12 = gp[5];
    float g20 = gp[6], g21 = gp[7], g22 = gp[8];
    float w[4][3];
    w[0][0] = g00;                w[0][1] = g01;                w[0][2] = g02;
    w[1][0] = 0.5f*(g00+g10+g20); w[1][1] = 0.5f*(g01+g11+g21); w[1][2] = 0.5f*(g02+g12+g22);
    w[2][0] = 0.5f*(g00-g10+g20); w[2][1] = 0.5f*(g01-g11+g21); w[2][2] = 0.5f*(g02-g12+g22);
    w[3][0] = g20;                w[3][1] = g21;                w[3][2] = g22;

    int kq = k >> 4, kl = k & 15;
    int ck = c >> 5;
    int lane = kl + (((c & 31) >> 3) << 4);
    int j = c & 7;
    #pragma unroll
    for (int a = 0; a < 4; ++a) {
        float uv[4];
        uv[0] = w[a][0];
        uv[1] = 0.5f * (w[a][0] + w[a][1] + w[a][2]);
        uv[2] = 0.5f * (w[a][0] - w[a][1] + w[a][2]);
        uv[3] = w[a][2];
        #pragma unroll
        for (int b = 0; b < 4; ++b) {
            int ab = a * 4 + b;
            size_t off = ((size_t)((ab * 2 + ck) * 4 + kq) * 64 + lane) * 8 + j;
            Uf[off] = (unsigned short)f2bf(uv[b]);
        }
    }
}

#define VSTRIDE 72                    // bytes per tm row (64 data + 8 pad)
#define VPLANE  (32 * VSTRIDE)        // 2304 B per ab-plane (32 tiles)
#define VBUF    (8 * VPLANE)          // 18432 B per buffer; 2 buffers = 36864 B
#define YSTRIDE 130                   // f32 words per k-plane staging (2x64 + 2 pad)

__global__ __launch_bounds__(512)
void winograd_main(const float* __restrict__ x, const unsigned short* __restrict__ Uf,
                   float* __restrict__ Y) {
    __shared__ __align__(16) char smem[2 * VBUF];   // 36864 B -> 4 blocks/CU

    const int tid  = threadIdx.x;
    const int lane = tid & 63;
    const int wv   = tid >> 6;                 // 0..7

    const int n   = blockIdx.x & 7;            // XCD pin
    const int r2  = blockIdx.x >> 3;           // 0..125
    const int uuh = r2 & 1;                    // uu half
    const int tb  = r2 >> 1;                   // 0..62 (tt row)

    const int mt = wv >> 2;                    // 0..1 M-tile (16 uu each)
    const int kq = wv & 3;                     // k-quarter

    const int kl = lane & 15;
    const int g4 = lane >> 4;

    f32x4 Yp[2][2];                             // [p][q] -- 16 VGPRs
    #pragma unroll
    for (int p = 0; p < 2; ++p)
        #pragma unroll
        for (int q = 0; q < 2; ++q)
            Yp[p][q] = (f32x4){0.f, 0.f, 0.f, 0.f};

    // transform mapping: tm_loc = local uu tile (0..31), cg = c-pair group (0..15).
    // uu_g==63 (uuh=1, tm_loc=31) is padding: clamp addr; discarded in epilogue.
    const int tm_loc = tid & 31;
    const int cg     = tid >> 5;
    const int uu_g   = uuh * 32 + tm_loc;
    const int tmcg   = (uu_g < T_TILES) ? uu_g : 0;

    // A-fragment read base (within an ab plane)
    const int tmA   = mt * 16 + kl;            // 0..31
    const int abyte = tmA * VSTRIDE + g4 * 16;

    const short8* UfV = (const short8*)Uf;

    // ---- transform one half-pass hp (CK-MAJOR: ck=hp>>1, P=hp&1) ----
    auto TRANSFORM = [&](int hp, int bufSel) {
        const int ck = hp >> 1;
        const int P  = hp & 1;
        const int xrow0 = 2 * tb + P;           // rows xrow0..xrow0+2 (max 127)
        float vv[2][8];
        #pragma unroll
        for (int hh = 0; hh < 2; ++hh) {
            const int c = ck * 32 + cg * 2 + hh;
            const float* xp = x + (((size_t)(n * 64 + c)) * HW + xrow0) * HW + 2 * tmcg;
            float ld[3][4];
            #pragma unroll
            for (int rr = 0; rr < 3; ++rr) {
                float2 lo = *reinterpret_cast<const float2*>(xp + rr * HW);
                float2 hi = *reinterpret_cast<const float2*>(xp + rr * HW + 2);
                ld[rr][0] = lo.x; ld[rr][1] = lo.y;
                ld[rr][2] = hi.x; ld[rr][3] = hi.y;
            }
            float wa[2][4];
            #pragma unroll
            for (int j = 0; j < 4; ++j) {
                if (P == 0) {
                    wa[0][j] = ld[0][j] - ld[2][j];   // a=0
                    wa[1][j] = ld[1][j] + ld[2][j];   // a=1
                } else {
                    wa[0][j] = ld[1][j] - ld[0][j];   // a=2
                    wa[1][j] = ld[0][j] - ld[2][j];   // a=3
                }
            }
            #pragma unroll
            for (int al = 0; al < 2; ++al) {
                vv[hh][al*4+0] = wa[al][0] - wa[al][2];
                vv[hh][al*4+1] = wa[al][1] + wa[al][2];
                vv[hh][al*4+2] = wa[al][2] - wa[al][1];
                vv[hh][al*4+3] = wa[al][1] - wa[al][3];
            }
        }
        const int wb = bufSel * VBUF + tm_loc * VSTRIDE + cg * 4;
        #pragma unroll
        for (int e = 0; e < 8; ++e)
            *reinterpret_cast<unsigned int*>(smem + e * VPLANE + wb) =
                pkbf2(vv[0][e], vv[1][e]);
    };

    // ---- pipeline: one barrier per half-pass; transform(p+1) || GEMM(p) ----
    TRANSFORM(0, 0);
    __syncthreads();

    #pragma unroll 1
    for (int p = 0; p < 4; ++p) {
        if (p < 3) TRANSFORM(p + 1, (p + 1) & 1);

        const int ck = p >> 1;                  // ck-major (matches TRANSFORM)
        const int P  = p & 1;
        const int bb = (p & 1) * VBUF;
        #pragma unroll
        for (int aa = 0; aa < 2; ++aa) {
            const int a = 2 * P + aa;
            f32x4 acc[4];
            #pragma unroll
            for (int b = 0; b < 4; ++b) acc[b] = (f32x4){0.f, 0.f, 0.f, 0.f};
            #pragma unroll
            for (int b = 0; b < 4; ++b) {
                const char* ap = smem + bb + (aa * 4 + b) * VPLANE + abyte;
                uint2 q0 = *reinterpret_cast<const uint2*>(ap);
                uint2 q1 = *reinterpret_cast<const uint2*>(ap + 8);
                uint4 t; t.x = q0.x; t.y = q0.y; t.z = q1.x; t.w = q1.y;
                short8 Af = *reinterpret_cast<short8*>(&t);
                short8 Bf = UfV[(size_t)(((a * 4 + b) * 2 + ck) * 4 + kq) * 64 + lane];
                acc[b] = __builtin_amdgcn_mfma_f32_16x16x32_bf16(Af, Bf, acc[b], 0, 0, 0);
            }
            // fold (linear in partial sums; order-invariant accumulation)
            f32x4 t0 = acc[0] + acc[1] + acc[2];
            f32x4 t1 = acc[1] - acc[2] - acc[3];
            if (a == 0) { Yp[0][0] += t0; Yp[0][1] += t1; }
            if (a == 1) { Yp[0][0] += t0; Yp[0][1] += t1;
                          Yp[1][0] += t0; Yp[1][1] += t1; }
            if (a == 2) { Yp[0][0] += t0; Yp[0][1] += t1;
                          Yp[1][0] -= t0; Yp[1][1] -= t1; }
            if (a == 3) { Yp[1][0] -= t0; Yp[1][1] -= t1; }
        }
        __syncthreads();
    }

    // ---- store: each wave stages its 16 finished planes (no merge),
    //      then plane-contiguous copy-out (256 B row chunks) ----
    float* Ys = reinterpret_cast<float*>(smem);
    {
        const int plane = kq * 16 + kl;         // = k (0..63)
        #pragma unroll
        for (int r = 0; r < 4; ++r) {
            const int uu_loc = mt * 16 + 4 * g4 + r;   // 0..31
            if (uuh * 32 + uu_loc < T_TILES) {
                #pragma unroll
                for (int p = 0; p < 2; ++p)
                    *reinterpret_cast<float2*>(Ys + plane * YSTRIDE + p * 64 + 2 * uu_loc)
                        = make_float2(Yp[p][0][r], Yp[p][1][r]);
            }
        }
    }
    __syncthreads();

    // copy out: 64 planes x 2 rows x 32 float2 = 4096 units / 512 thr = 8 each
    #pragma unroll
    for (int i = 0; i < 8; ++i) {
        const int unit  = tid + 512 * i;        // 0..4095
        const int plane = unit >> 6;            // 0..63
        const int sub   = unit & 63;
        const int row   = sub >> 5;             // 0..1
        const int c2    = sub & 31;
        const int col_g = uuh * 64 + 2 * c2;
        if (col_g <= 124) {
            float2 v = *reinterpret_cast<const float2*>(
                Ys + plane * YSTRIDE + row * 64 + 2 * c2);
            *reinterpret_cast<float2*>(
                Y + ((size_t)(n * 64 + plane)) * (OW * OW)
                  + (size_t)(2 * tb + row) * OW + col_g) = v;
        }
    }
}

extern "C" void kernel_launch(void* const* d_in, const int* in_sizes, int n_in,
                              void* d_out, int out_size, void* d_ws, size_t ws_size,
                              hipStream_t stream) {
    const float* x    = (const float*)d_in[0];
    const float* filt = (const float*)d_in[1];
    float* Y = (float*)d_out;
    unsigned short* Uf = (unsigned short*)d_ws;    // 128 KB bf16 U fragments

    filter_transform<<<16, 256, 0, stream>>>(filt, Uf);

    winograd_main<<<dim3(1008), 512, 0, stream>>>(x, Uf, Y);
}

// Round 23
// 32.179 us; speedup vs baseline: 1.0776x; 1.0201x over previous
//
#include <hip/hip_runtime.h>
#include <hip/hip_bf16.h>

// Winograd F(2x2,3x3) via bf16 MFMA.  == R19, the verified optimum (31.8 us) ==
// x (8,64,128,128) f32, filt (64,64,3,3) f32 -> Y (8,64,126,126) f32
// Block = (n, ONE tt row, uu-HALF: 32 tiles, ALL 64 k, ALL 64 c). 512 thr = 8 waves.
// Grid 1008 = 8 n x 63 tt x 2 uuh; blockIdx&7 = n -> image pinned to one XCD.
// 4 half-passes (2 a-pairs x 2 c-halves), DOUBLE-BUFFERED V (2 x 18.4 KB):
//   transform(p+1) || GEMM(p) per barrier window; barrier domain = 8 waves,
//   4 independent blocks/CU fill each other's load-burst bubbles.
// Wave = (mt 2, kq 4); Yp=[2][2]=16 regs (VGPR<=64 tier).
// Rejected by measurement: R20 4-wave blocks (-4%), R21 setprio (-9%),
// R22 ck-major order (-3%), R12 T14 reg-hoist (reg tier), R10/R11 min-waves
// coercion (spill). No min-waves bound.

#define T_TILES 63
#define HW 128
#define OW 126

typedef __attribute__((ext_vector_type(8))) short short8;   // 8 bf16
typedef __attribute__((ext_vector_type(4))) float f32x4;

static __device__ __forceinline__ unsigned int f2bf(float f) {
    unsigned int u = __float_as_uint(f);
    return (u + 0x7FFFu + ((u >> 16) & 1u)) >> 16;   // RNE bf16
}

static __device__ __forceinline__ unsigned int pkbf2(float lo, float hi) {
    __hip_bfloat162 t;
    t.x = __float2bfloat16(lo);
    t.y = __float2bfloat16(hi);
    unsigned int r;
    __builtin_memcpy(&r, &t, 4);
    return r;                                   // v_cvt_pk_bf16_f32
}

// U_frag layout: frag[(ab*2+ck)*4+kq][lane 0..63][j 0..7] bf16 (128 KB)
// B-operand lane l holds B[c'=(l>>4)*8+j (+32*ck)][k=(l&15)+16*kq]
__global__ __launch_bounds__(256)
void filter_transform(const float* __restrict__ g, unsigned short* __restrict__ Uf) {
    int idx = blockIdx.x * 256 + threadIdx.x;   // k*64 + c
    if (idx >= 64 * 64) return;
    int k = idx >> 6, c = idx & 63;
    const float* gp = g + idx * 9;
    float g00 = gp[0], g01 = gp[1], g02 = gp[2];
    float g10 = gp[3], g11 = gp[4], g12 = gp[5];
    float g20 = gp[6], g21 = gp[7], g22 = gp[8];
    float w[4][3];
    w[0][0] = g00;                w[0][1] = g01;                w[0][2] = g02;
    w[1][0] = 0.5f*(g00+g10+g20); w[1][1] = 0.5f*(g01+g11+g21); w[1][2] = 0.5f*(g02+g12+g22);
    w[2][0] = 0.5f*(g00-g10+g20); w[2][1] = 0.5f*(g01-g11+g21); w[2][2] = 0.5f*(g02-g12+g22);
    w[3][0] = g20;                w[3][1] = g21;                w[3][2] = g22;

    int kq = k >> 4, kl = k & 15;
    int ck = c >> 5;
    int lane = kl + (((c & 31) >> 3) << 4);
    int j = c & 7;
    #pragma unroll
    for (int a = 0; a < 4; ++a) {
        float uv[4];
        uv[0] = w[a][0];
        uv[1] = 0.5f * (w[a][0] + w[a][1] + w[a][2]);
        uv[2] = 0.5f * (w[a][0] - w[a][1] + w[a][2]);
        uv[3] = w[a][2];
        #pragma unroll
        for (int b = 0; b < 4; ++b) {
            int ab = a * 4 + b;
            size_t off = ((size_t)((ab * 2 + ck) * 4 + kq) * 64 + lane) * 8 + j;
            Uf[off] = (unsigned short)f2bf(uv[b]);
        }
    }
}

#define VSTRIDE 72                    // bytes per tm row (64 data + 8 pad)
#define VPLANE  (32 * VSTRIDE)        // 2304 B per ab-plane (32 tiles)
#define VBUF    (8 * VPLANE)          // 18432 B per buffer; 2 buffers = 36864 B
#define YSTRIDE 130                   // f32 words per k-plane staging (2x64 + 2 pad)

__global__ __launch_bounds__(512)
void winograd_main(const float* __restrict__ x, const unsigned short* __restrict__ Uf,
                   float* __restrict__ Y) {
    __shared__ __align__(16) char smem[2 * VBUF];   // 36864 B -> 4 blocks/CU

    const int tid  = threadIdx.x;
    const int lane = tid & 63;
    const int wv   = tid >> 6;                 // 0..7

    const int n   = blockIdx.x & 7;            // XCD pin
    const int r2  = blockIdx.x >> 3;           // 0..125
    const int uuh = r2 & 1;                    // uu half
    const int tb  = r2 >> 1;                   // 0..62 (tt row)

    const int mt = wv >> 2;                    // 0..1 M-tile (16 uu each)
    const int kq = wv & 3;                     // k-quarter

    const int kl = lane & 15;
    const int g4 = lane >> 4;

    f32x4 Yp[2][2];                             // [p][q] -- 16 VGPRs
    #pragma unroll
    for (int p = 0; p < 2; ++p)
        #pragma unroll
        for (int q = 0; q < 2; ++q)
            Yp[p][q] = (f32x4){0.f, 0.f, 0.f, 0.f};

    // transform mapping: tm_loc = local uu tile (0..31), cg = c-pair group (0..15).
    // uu_g==63 (uuh=1, tm_loc=31) is padding: clamp addr; discarded in epilogue.
    const int tm_loc = tid & 31;
    const int cg     = tid >> 5;
    const int uu_g   = uuh * 32 + tm_loc;
    const int tmcg   = (uu_g < T_TILES) ? uu_g : 0;

    // A-fragment read base (within an ab plane)
    const int tmA   = mt * 16 + kl;            // 0..31
    const int abyte = tmA * VSTRIDE + g4 * 16;

    const short8* UfV = (const short8*)Uf;

    // ---- transform one half-pass hp = (P, ck) into buffer bufSel ----
    auto TRANSFORM = [&](int hp, int bufSel) {
        const int P  = hp >> 1;
        const int ck = hp & 1;
        const int xrow0 = 2 * tb + P;           // rows xrow0..xrow0+2 (max 127)
        float vv[2][8];
        #pragma unroll
        for (int hh = 0; hh < 2; ++hh) {
            const int c = ck * 32 + cg * 2 + hh;
            const float* xp = x + (((size_t)(n * 64 + c)) * HW + xrow0) * HW + 2 * tmcg;
            float ld[3][4];
            #pragma unroll
            for (int rr = 0; rr < 3; ++rr) {
                float2 lo = *reinterpret_cast<const float2*>(xp + rr * HW);
                float2 hi = *reinterpret_cast<const float2*>(xp + rr * HW + 2);
                ld[rr][0] = lo.x; ld[rr][1] = lo.y;
                ld[rr][2] = hi.x; ld[rr][3] = hi.y;
            }
            float wa[2][4];
            #pragma unroll
            for (int j = 0; j < 4; ++j) {
                if (P == 0) {
                    wa[0][j] = ld[0][j] - ld[2][j];   // a=0
                    wa[1][j] = ld[1][j] + ld[2][j];   // a=1
                } else {
                    wa[0][j] = ld[1][j] - ld[0][j];   // a=2
                    wa[1][j] = ld[0][j] - ld[2][j];   // a=3
                }
            }
            #pragma unroll
            for (int al = 0; al < 2; ++al) {
                vv[hh][al*4+0] = wa[al][0] - wa[al][2];
                vv[hh][al*4+1] = wa[al][1] + wa[al][2];
                vv[hh][al*4+2] = wa[al][2] - wa[al][1];
                vv[hh][al*4+3] = wa[al][1] - wa[al][3];
            }
        }
        const int wb = bufSel * VBUF + tm_loc * VSTRIDE + cg * 4;
        #pragma unroll
        for (int e = 0; e < 8; ++e)
            *reinterpret_cast<unsigned int*>(smem + e * VPLANE + wb) =
                pkbf2(vv[0][e], vv[1][e]);
    };

    // ---- pipeline: one barrier per half-pass; transform(p+1) || GEMM(p) ----
    TRANSFORM(0, 0);
    __syncthreads();

    #pragma unroll 1
    for (int p = 0; p < 4; ++p) {
        if (p < 3) TRANSFORM(p + 1, (p + 1) & 1);

        const int P  = p >> 1;
        const int ck = p & 1;
        const int bb = (p & 1) * VBUF;
        #pragma unroll
        for (int aa = 0; aa < 2; ++aa) {
            const int a = 2 * P + aa;
            f32x4 acc[4];
            #pragma unroll
            for (int b = 0; b < 4; ++b) acc[b] = (f32x4){0.f, 0.f, 0.f, 0.f};
            #pragma unroll
            for (int b = 0; b < 4; ++b) {
                const char* ap = smem + bb + (aa * 4 + b) * VPLANE + abyte;
                uint2 q0 = *reinterpret_cast<const uint2*>(ap);
                uint2 q1 = *reinterpret_cast<const uint2*>(ap + 8);
                uint4 t; t.x = q0.x; t.y = q0.y; t.z = q1.x; t.w = q1.y;
                short8 Af = *reinterpret_cast<short8*>(&t);
                short8 Bf = UfV[(size_t)(((a * 4 + b) * 2 + ck) * 4 + kq) * 64 + lane];
                acc[b] = __builtin_amdgcn_mfma_f32_16x16x32_bf16(Af, Bf, acc[b], 0, 0, 0);
            }
            // fold (linear in partial sums; ck halves accumulate)
            f32x4 t0 = acc[0] + acc[1] + acc[2];
            f32x4 t1 = acc[1] - acc[2] - acc[3];
            if (a == 0) { Yp[0][0] += t0; Yp[0][1] += t1; }
            if (a == 1) { Yp[0][0] += t0; Yp[0][1] += t1;
                          Yp[1][0] += t0; Yp[1][1] += t1; }
            if (a == 2) { Yp[0][0] += t0; Yp[0][1] += t1;
                          Yp[1][0] -= t0; Yp[1][1] -= t1; }
            if (a == 3) { Yp[1][0] -= t0; Yp[1][1] -= t1; }
        }
        __syncthreads();
    }

    // ---- store: each wave stages its 16 finished planes (no merge),
    //      then plane-contiguous copy-out (256 B row chunks) ----
    float* Ys = reinterpret_cast<float*>(smem);
    {
        const int plane = kq * 16 + kl;         // = k (0..63)
        #pragma unroll
        for (int r = 0; r < 4; ++r) {
            const int uu_loc = mt * 16 + 4 * g4 + r;   // 0..31
            if (uuh * 32 + uu_loc < T_TILES) {
                #pragma unroll
                for (int p = 0; p < 2; ++p)
                    *reinterpret_cast<float2*>(Ys + plane * YSTRIDE + p * 64 + 2 * uu_loc)
                        = make_float2(Yp[p][0][r], Yp[p][1][r]);
            }
        }
    }
    __syncthreads();

    // copy out: 64 planes x 2 rows x 32 float2 = 4096 units / 512 thr = 8 each
    #pragma unroll
    for (int i = 0; i < 8; ++i) {
        const int unit  = tid + 512 * i;        // 0..4095
        const int plane = unit >> 6;            // 0..63
        const int sub   = unit & 63;
        const int row   = sub >> 5;             // 0..1
        const int c2    = sub & 31;
        const int col_g = uuh * 64 + 2 * c2;
        if (col_g <= 124) {
            float2 v = *reinterpret_cast<const float2*>(
                Ys + plane * YSTRIDE + row * 64 + 2 * c2);
            *reinterpret_cast<float2*>(
                Y + ((size_t)(n * 64 + plane)) * (OW * OW)
                  + (size_t)(2 * tb + row) * OW + col_g) = v;
        }
    }
}

extern "C" void kernel_launch(void* const* d_in, const int* in_sizes, int n_in,
                              void* d_out, int out_size, void* d_ws, size_t ws_size,
                              hipStream_t stream) {
    const float* x    = (const float*)d_in[0];
    const float* filt = (const float*)d_in[1];
    float* Y = (float*)d_out;
    unsigned short* Uf = (unsigned short*)d_ws;    // 128 KB bf16 U fragments

    filter_transform<<<16, 256, 0, stream>>>(filt, Uf);

    winograd_main<<<dim3(1008), 512, 0, stream>>>(x, Uf, Y);
}